// Round 1
// baseline (1018.657 us; speedup 1.0000x reference)
//
#include <hip/hip_runtime.h>
#include <math.h>

#define L 768
#define CS 256
#define CZ 128
#define H 8
#define CH 32
#define NPQK 4
#define NPV 8
#define LL (L*L)

// ---------------- K1: LayerNorm over s rows ----------------
__global__ void k_ln_s(const float* __restrict__ s, const float* __restrict__ w,
                       const float* __restrict__ b, float* __restrict__ out) {
  int i = blockIdx.x, t = threadIdx.x;
  __shared__ float red[256];
  float x = s[i*CS + t];
  red[t] = x; __syncthreads();
  for (int s2=128; s2>0; s2>>=1){ if (t<s2) red[t]+=red[t+s2]; __syncthreads(); }
  float mean = red[0] * (1.0f/CS); __syncthreads();
  float d = x - mean;
  red[t] = d*d; __syncthreads();
  for (int s2=128; s2>0; s2>>=1){ if (t<s2) red[t]+=red[t+s2]; __syncthreads(); }
  float var = red[0] * (1.0f/CS);
  float rstd = rsqrtf(var + 1e-5f);
  out[i*CS+t] = d*rstd*w[t] + b[t];
}

// ---------------- K2: all projections of s + rigid transform ----------------
__global__ void k_proj(const float* __restrict__ s_n,
                       const float* __restrict__ Wq, const float* __restrict__ Wk, const float* __restrict__ Wv,
                       const float* __restrict__ Wqp, const float* __restrict__ Wkp, const float* __restrict__ Wvp,
                       const float* __restrict__ R, const float* __restrict__ t,
                       float* __restrict__ q, float* __restrict__ k, float* __restrict__ v,
                       float* __restrict__ qpg, float* __restrict__ kpg, float* __restrict__ vpg) {
  int i = blockIdx.x, tid = threadIdx.x;
  __shared__ float srow[256];
  __shared__ float qraw[96], kraw[96], vraw[192];
  __shared__ float Rl[9], tl[3];
  srow[tid] = s_n[i*CS + tid];
  if (tid < 9) Rl[tid] = R[i*9 + tid];
  if (tid >= 16 && tid < 19) tl[tid-16] = t[i*3 + (tid-16)];
  __syncthreads();
  float aq=0.f, ak=0.f, av=0.f;
  #pragma unroll 4
  for (int c=0;c<256;c++){ float sv=srow[c];
    aq = fmaf(sv, Wq[c*256+tid], aq);
    ak = fmaf(sv, Wk[c*256+tid], ak);
    av = fmaf(sv, Wv[c*256+tid], av); }
  q[i*256+tid]=aq; k[i*256+tid]=ak; v[i*256+tid]=av;
  if (tid < 96){
    float a1=0.f, a2=0.f;
    #pragma unroll 4
    for (int c=0;c<256;c++){ float sv=srow[c];
      a1 = fmaf(sv, Wqp[c*96+tid], a1);
      a2 = fmaf(sv, Wkp[c*96+tid], a2); }
    qraw[tid]=a1; kraw[tid]=a2;
  }
  if (tid < 192){
    float a3=0.f;
    #pragma unroll 4
    for (int c=0;c<256;c++) a3 = fmaf(srow[c], Wvp[c*192+tid], a3);
    vraw[tid]=a3;
  }
  __syncthreads();
  if (tid < 32){
    int b0 = tid*3;
    float px=qraw[b0], py=qraw[b0+1], pz=qraw[b0+2];
    #pragma unroll
    for (int x=0;x<3;x++)
      qpg[i*96 + b0 + x] = Rl[x*3]*px + Rl[x*3+1]*py + Rl[x*3+2]*pz + tl[x];
  } else if (tid < 64){
    int b0 = (tid-32)*3;
    float px=kraw[b0], py=kraw[b0+1], pz=kraw[b0+2];
    #pragma unroll
    for (int x=0;x<3;x++)
      kpg[i*96 + b0 + x] = Rl[x*3]*px + Rl[x*3+1]*py + Rl[x*3+2]*pz + tl[x];
  } else if (tid < 128){
    int b0 = (tid-64)*3;
    float px=vraw[b0], py=vraw[b0+1], pz=vraw[b0+2];
    #pragma unroll
    for (int x=0;x<3;x++)
      vpg[i*192 + b0 + x] = Rl[x*3]*px + Rl[x*3+1]*py + Rl[x*3+2]*pz + tl[x];
  }
}

// ---------------- K3: fused LN(z) + pair_bias + pair_v ----------------
// Tile: one i, 64 consecutive j. pb written with [h][i][j] layout (into d_out attn region).
__global__ void k_zfuse(const float* __restrict__ z, const float* __restrict__ lzw, const float* __restrict__ lzb,
                        const float* __restrict__ Wpb, const float* __restrict__ Wpo,
                        float* __restrict__ pb, float* __restrict__ pv) {
  int i = blockIdx.x, jt = blockIdx.y, tid = threadIdx.x;
  int j0 = jt * 64;
  __shared__ float zn[64*129];
  __shared__ float Wl[128*40];   // Wl[c*40+o]: o<8 -> pair_bias head, else pair_v dim o-8
  for (int idx=tid; idx<128*40; idx+=256){
    int c = idx/40, o = idx%40;
    Wl[idx] = (o<8) ? Wpb[c*8+o] : Wpo[c*32 + (o-8)];
  }
  const float* zb = z + ((size_t)i*L + j0)*CZ;
  for (int kk=0; kk<32; kk++){
    int idx = kk*256 + tid;
    int r = idx >> 7, c = idx & 127;
    zn[r*129 + c] = zb[idx];
  }
  __syncthreads();
  // LN: 4 threads per row
  {
    int r = tid >> 2, sub = tid & 3;
    float sm=0.f, sq=0.f;
    for (int c=sub; c<128; c+=4){ float xv = zn[r*129+c]; sm+=xv; sq+=xv*xv; }
    sm += __shfl_xor(sm,1); sq += __shfl_xor(sq,1);
    sm += __shfl_xor(sm,2); sq += __shfl_xor(sq,2);
    float mean = sm * (1.0f/CZ);
    float var  = sq * (1.0f/CZ) - mean*mean;
    float rstd = rsqrtf(var + 1e-5f);
    for (int c=sub; c<128; c+=4){
      float xv = zn[r*129+c];
      zn[r*129+c] = (xv-mean)*rstd*lzw[c] + lzb[c];
    }
  }
  __syncthreads();
  // register-tiled 64x40 = (64 rows x 128) @ (128 x 40)
  int og = tid >> 5;          // 0..7 -> outs og*5 .. og*5+4
  int rg = tid & 31;          // rows rg*2, rg*2+1
  int ob = og*5;
  float acc0[5] = {0,0,0,0,0};
  float acc1[5] = {0,0,0,0,0};
  #pragma unroll 2
  for (int c=0;c<128;c++){
    float z0 = zn[(rg*2  )*129 + c];
    float z1 = zn[(rg*2+1)*129 + c];
    #pragma unroll
    for (int oo=0;oo<5;oo++){
      float wv = Wl[c*40 + ob + oo];
      acc0[oo] = fmaf(z0, wv, acc0[oo]);
      acc1[oo] = fmaf(z1, wv, acc1[oo]);
    }
  }
  #pragma unroll
  for (int rr=0; rr<2; rr++){
    int j = j0 + rg*2 + rr;
    const float* acc = rr ? acc1 : acc0;
    #pragma unroll
    for (int oo=0;oo<5;oo++){
      int o = ob + oo;
      float val = acc[oo];
      if (o < 8) pb[(size_t)o*LL + (size_t)i*L + j] = val;
      else       pv[((size_t)i*L + j)*32 + (o-8)] = val;
    }
  }
}

// ---------------- K4: attention per (h,i) ----------------
__global__ void k_attn(const float* __restrict__ q, const float* __restrict__ k, const float* __restrict__ v,
                       const float* __restrict__ qpg, const float* __restrict__ kpg, const float* __restrict__ vpg,
                       float* __restrict__ pb_attn, const float* __restrict__ pv,
                       const float* __restrict__ R, const float* __restrict__ t,
                       const float* __restrict__ point_weights, const float* __restrict__ mask,
                       float* __restrict__ su_pre) {
  int i = blockIdx.x, h = blockIdx.y, tid = threadIdx.x;
  __shared__ float qrow[32], qp[12], Rl[9], tl[3];
  __shared__ float attn_lds[768];
  __shared__ float red[256];
  __shared__ float partial[60][4];
  __shared__ float ptg[24], ptl[24];
  if (tid < 32) qrow[tid] = q[i*256 + h*32 + tid];
  if (tid >= 32 && tid < 44) qp[tid-32] = qpg[i*96 + h*12 + (tid-32)];
  if (tid >= 64 && tid < 73) Rl[tid-64] = R[i*9 + (tid-64)];
  if (tid >= 80 && tid < 83) tl[tid-80] = t[i*3 + (tid-80)];
  float pwv = log1pf(expf(point_weights[h]));
  float mi = mask[i];
  __syncthreads();

  float logits[3];
  float lmax = -1e30f;
  #pragma unroll
  for (int rep=0; rep<3; rep++){
    int j = rep*256 + tid;
    const float* kr = k + j*256 + h*32;
    float dot = 0.f;
    #pragma unroll
    for (int c=0;c<32;c++) dot = fmaf(qrow[c], kr[c], dot);
    const float* kp = kpg + j*96 + h*12;
    float sq = 0.f;
    #pragma unroll
    for (int pc=0;pc<12;pc++){ float d = qp[pc]-kp[pc]; sq = fmaf(d,d,sq); }
    float lg = dot*0.17677669529663687f + pb_attn[((size_t)h*L + i)*L + j] - 0.5f*pwv*sq;
    if (mi*mask[j] == 0.f) lg = -1e9f;
    logits[rep] = lg;
    lmax = fmaxf(lmax, lg);
  }
  red[tid] = lmax; __syncthreads();
  for (int s2=128; s2>0; s2>>=1){ if (tid<s2) red[tid]=fmaxf(red[tid],red[tid+s2]); __syncthreads(); }
  float bmax = red[0]; __syncthreads();
  float lsum = 0.f;
  #pragma unroll
  for (int rep=0; rep<3; rep++){
    float e = expf(logits[rep]-bmax);
    attn_lds[rep*256+tid] = e; lsum += e;
  }
  red[tid] = lsum; __syncthreads();
  for (int s2=128; s2>0; s2>>=1){ if (tid<s2) red[tid]+=red[tid+s2]; __syncthreads(); }
  float inv = 1.0f/red[0];
  #pragma unroll
  for (int rep=0; rep<3; rep++){
    int j = rep*256 + tid;
    float a = attn_lds[j]*inv;
    attn_lds[j] = a;
    pb_attn[((size_t)h*L + i)*L + j] = a;   // overwrite pair_bias slot with attn output
  }
  __syncthreads();

  // 60 weighted-sum outputs: 0..31 scalar, 32..55 point(global), 56..59 pair
  if (tid < 240){
    int o = tid % 60, chunk = tid / 60;
    const float* base; size_t stride;
    if (o < 32)      { base = v   + h*32 + o;                          stride = 256; }
    else if (o < 56) { base = vpg + h*24 + (o-32);                     stride = 192; }
    else             { base = pv  + (size_t)i*L*32 + h*4 + (o-56);     stride = 32;  }
    float val = 0.f;
    int jbase = chunk*192;
    #pragma unroll 4
    for (int jj=0; jj<192; jj++){
      int j = jbase + jj;
      val = fmaf(attn_lds[j], base[(size_t)j*stride], val);
    }
    partial[o][chunk] = val;
  }
  __syncthreads();
  if (tid < 60){
    float val = partial[tid][0]+partial[tid][1]+partial[tid][2]+partial[tid][3];
    if (tid < 32)      su_pre[i*544 + h*32 + tid] = val;                 // scalar_out
    else if (tid < 56) ptg[tid-32] = val;                                // point global
    else               su_pre[i*544 + 512 + h*4 + (tid-56)] = val;       // pair_out
  }
  __syncthreads();
  if (tid < 24){
    int p = tid/3, y = tid%3;
    float lv = 0.f;
    #pragma unroll
    for (int x=0;x<3;x++) lv = fmaf(Rl[x*3+y], ptg[p*3+x]-tl[x], lv);
    ptl[tid] = lv;
    su_pre[i*544 + 256 + h*24 + tid] = lv;                               // point_out (local)
  }
  __syncthreads();
  if (tid < 8){
    float a0=ptl[tid*3], a1=ptl[tid*3+1], a2=ptl[tid*3+2];
    su_pre[i*544 + 448 + h*8 + tid] = sqrtf(a0*a0+a1*a1+a2*a2 + 1e-8f);  // point_norms
  }
}

// ---------------- K5: output projection ----------------
__global__ void k_out(const float* __restrict__ su_pre, const float* __restrict__ W_out,
                      const float* __restrict__ b_out, const float* __restrict__ mask,
                      float* __restrict__ out) {
  int i = blockIdx.x, tid = threadIdx.x;
  __shared__ float srow[544];
  for (int idx=tid; idx<544; idx+=256) srow[idx] = su_pre[i*544+idx];
  __syncthreads();
  float acc = b_out[tid];
  #pragma unroll 4
  for (int c=0;c<544;c++) acc = fmaf(srow[c], W_out[c*256+tid], acc);
  out[i*256+tid] = acc * mask[i];
}

extern "C" void kernel_launch(void* const* d_in, const int* in_sizes, int n_in,
                              void* d_out, int out_size, void* d_ws, size_t ws_size,
                              hipStream_t stream) {
  const float* s    = (const float*)d_in[0];
  const float* z    = (const float*)d_in[1];
  const float* R    = (const float*)d_in[2];
  const float* t    = (const float*)d_in[3];
  const float* mask = (const float*)d_in[4];
  const float* lsw  = (const float*)d_in[5];
  const float* lsb  = (const float*)d_in[6];
  const float* lzw  = (const float*)d_in[7];
  const float* lzb  = (const float*)d_in[8];
  const float* Wq   = (const float*)d_in[9];
  const float* Wk   = (const float*)d_in[10];
  const float* Wv   = (const float*)d_in[11];
  const float* Wpb  = (const float*)d_in[12];
  const float* Wqp  = (const float*)d_in[13];
  const float* Wkp  = (const float*)d_in[14];
  const float* Wvp  = (const float*)d_in[15];
  const float* pwts = (const float*)d_in[16];
  const float* Wpo  = (const float*)d_in[17];
  const float* Wout = (const float*)d_in[18];
  const float* bout = (const float*)d_in[19];

  float* out0 = (float*)d_out;            // s_update: 768*256
  float* attn = out0 + (size_t)L*CS;      // attn: 8*768*768 (also used as pair_bias buffer)

  float* ws   = (float*)d_ws;
  float* s_n  = ws;                        size_t off = (size_t)L*CS;
  float* q    = ws + off;                  off += (size_t)L*CS;
  float* k    = ws + off;                  off += (size_t)L*CS;
  float* v    = ws + off;                  off += (size_t)L*CS;
  float* qpg  = ws + off;                  off += (size_t)L*96;
  float* kpg  = ws + off;                  off += (size_t)L*96;
  float* vpg  = ws + off;                  off += (size_t)L*192;
  float* pv   = ws + off;                  off += (size_t)LL*32;
  float* su   = ws + off;                  off += (size_t)L*544;

  k_ln_s<<<L, 256, 0, stream>>>(s, lsw, lsb, s_n);
  k_proj<<<L, 256, 0, stream>>>(s_n, Wq, Wk, Wv, Wqp, Wkp, Wvp, R, t,
                                q, k, v, qpg, kpg, vpg);
  k_zfuse<<<dim3(L, L/64), 256, 0, stream>>>(z, lzw, lzb, Wpb, Wpo, attn, pv);
  k_attn<<<dim3(L, H), 256, 0, stream>>>(q, k, v, qpg, kpg, vpg, attn, pv,
                                         R, t, pwts, mask, su);
  k_out<<<L, 256, 0, stream>>>(su, Wout, bout, mask, out0);
}

// Round 2
// 890.374 us; speedup vs baseline: 1.1441x; 1.1441x over previous
//
#include <hip/hip_runtime.h>
#include <math.h>

#define L 768
#define CS 256
#define CZ 128
#define H 8
#define LL (L*L)

// ---------------- K1: LayerNorm over s rows ----------------
__global__ void k_ln_s(const float* __restrict__ s, const float* __restrict__ w,
                       const float* __restrict__ b, float* __restrict__ out) {
  int i = blockIdx.x, t = threadIdx.x;
  __shared__ float red[256];
  float x = s[i*CS + t];
  red[t] = x; __syncthreads();
  for (int s2=128; s2>0; s2>>=1){ if (t<s2) red[t]+=red[t+s2]; __syncthreads(); }
  float mean = red[0] * (1.0f/CS); __syncthreads();
  float d = x - mean;
  red[t] = d*d; __syncthreads();
  for (int s2=128; s2>0; s2>>=1){ if (t<s2) red[t]+=red[t+s2]; __syncthreads(); }
  float var = red[0] * (1.0f/CS);
  float rstd = rsqrtf(var + 1e-5f);
  out[i*CS+t] = d*rstd*w[t] + b[t];
}

// ---------------- K2: all projections of s + rigid transform ----------------
// kT: [256 outdim][768 i]  (transposed for coalesced j-reads in attention)
// kpgT: [96 outdim][768 i]
__global__ void k_proj(const float* __restrict__ s_n,
                       const float* __restrict__ Wq, const float* __restrict__ Wk, const float* __restrict__ Wv,
                       const float* __restrict__ Wqp, const float* __restrict__ Wkp, const float* __restrict__ Wvp,
                       const float* __restrict__ R, const float* __restrict__ t,
                       float* __restrict__ q, float* __restrict__ kT, float* __restrict__ v,
                       float* __restrict__ qpg, float* __restrict__ kpgT, float* __restrict__ vpg) {
  int i = blockIdx.x, tid = threadIdx.x;
  __shared__ float srow[256];
  __shared__ float qraw[96], kraw[96], vraw[192];
  __shared__ float Rl[9], tl[3];
  srow[tid] = s_n[i*CS + tid];
  if (tid < 9) Rl[tid] = R[i*9 + tid];
  if (tid >= 16 && tid < 19) tl[tid-16] = t[i*3 + (tid-16)];
  __syncthreads();
  float aq=0.f, ak=0.f, av=0.f;
  #pragma unroll 4
  for (int c=0;c<256;c++){ float sv=srow[c];
    aq = fmaf(sv, Wq[c*256+tid], aq);
    ak = fmaf(sv, Wk[c*256+tid], ak);
    av = fmaf(sv, Wv[c*256+tid], av); }
  q[i*256+tid]=aq; kT[(size_t)tid*L + i]=ak; v[i*256+tid]=av;
  if (tid < 96){
    float a1=0.f, a2=0.f;
    #pragma unroll 4
    for (int c=0;c<256;c++){ float sv=srow[c];
      a1 = fmaf(sv, Wqp[c*96+tid], a1);
      a2 = fmaf(sv, Wkp[c*96+tid], a2); }
    qraw[tid]=a1; kraw[tid]=a2;
  }
  if (tid < 192){
    float a3=0.f;
    #pragma unroll 4
    for (int c=0;c<256;c++) a3 = fmaf(srow[c], Wvp[c*192+tid], a3);
    vraw[tid]=a3;
  }
  __syncthreads();
  if (tid < 32){
    int b0 = tid*3;
    float px=qraw[b0], py=qraw[b0+1], pz=qraw[b0+2];
    #pragma unroll
    for (int x=0;x<3;x++)
      qpg[i*96 + b0 + x] = Rl[x*3]*px + Rl[x*3+1]*py + Rl[x*3+2]*pz + tl[x];
  } else if (tid < 64){
    int b0 = (tid-32)*3;
    float px=kraw[b0], py=kraw[b0+1], pz=kraw[b0+2];
    #pragma unroll
    for (int x=0;x<3;x++)
      kpgT[(size_t)(b0+x)*L + i] = Rl[x*3]*px + Rl[x*3+1]*py + Rl[x*3+2]*pz + tl[x];
  } else if (tid < 128){
    int b0 = (tid-64)*3;
    float px=vraw[b0], py=vraw[b0+1], pz=vraw[b0+2];
    #pragma unroll
    for (int x=0;x<3;x++)
      vpg[i*192 + b0 + x] = Rl[x*3]*px + Rl[x*3+1]*py + Rl[x*3+2]*pz + tl[x];
  }
}

// ---------------- K3: fused LN(z) + pair_bias + pair_v ----------------
__global__ void k_zfuse(const float* __restrict__ z, const float* __restrict__ lzw, const float* __restrict__ lzb,
                        const float* __restrict__ Wpb, const float* __restrict__ Wpo,
                        float* __restrict__ pb, float* __restrict__ pv) {
  int i = blockIdx.x, jt = blockIdx.y, tid = threadIdx.x;
  int j0 = jt * 64;
  __shared__ float zn[64*129];
  __shared__ float Wl[128*40];
  for (int idx=tid; idx<128*40; idx+=256){
    int c = idx/40, o = idx%40;
    Wl[idx] = (o<8) ? Wpb[c*8+o] : Wpo[c*32 + (o-8)];
  }
  const float* zb = z + ((size_t)i*L + j0)*CZ;
  for (int kk=0; kk<32; kk++){
    int idx = kk*256 + tid;
    int r = idx >> 7, c = idx & 127;
    zn[r*129 + c] = zb[idx];
  }
  __syncthreads();
  {
    int r = tid >> 2, sub = tid & 3;
    float sm=0.f, sq=0.f;
    for (int c=sub; c<128; c+=4){ float xv = zn[r*129+c]; sm+=xv; sq+=xv*xv; }
    sm += __shfl_xor(sm,1); sq += __shfl_xor(sq,1);
    sm += __shfl_xor(sm,2); sq += __shfl_xor(sq,2);
    float mean = sm * (1.0f/CZ);
    float var  = sq * (1.0f/CZ) - mean*mean;
    float rstd = rsqrtf(var + 1e-5f);
    for (int c=sub; c<128; c+=4){
      float xv = zn[r*129+c];
      zn[r*129+c] = (xv-mean)*rstd*lzw[c] + lzb[c];
    }
  }
  __syncthreads();
  int og = tid >> 5;
  int rg = tid & 31;
  int ob = og*5;
  float acc0[5] = {0,0,0,0,0};
  float acc1[5] = {0,0,0,0,0};
  #pragma unroll 2
  for (int c=0;c<128;c++){
    float z0 = zn[(rg*2  )*129 + c];
    float z1 = zn[(rg*2+1)*129 + c];
    #pragma unroll
    for (int oo=0;oo<5;oo++){
      float wv = Wl[c*40 + ob + oo];
      acc0[oo] = fmaf(z0, wv, acc0[oo]);
      acc1[oo] = fmaf(z1, wv, acc1[oo]);
    }
  }
  #pragma unroll
  for (int rr=0; rr<2; rr++){
    int j = j0 + rg*2 + rr;
    const float* acc = rr ? acc1 : acc0;
    #pragma unroll
    for (int oo=0;oo<5;oo++){
      int o = ob + oo;
      float val = acc[oo];
      if (o < 8) pb[(size_t)o*LL + (size_t)i*L + j] = val;
      else       pv[((size_t)i*L + j)*32 + (o-8)] = val;
    }
  }
}

// ---------------- K4: fused attention, one block per i, all 8 heads ----------------
__global__ __launch_bounds__(256) void k_attn_fused(
    const float* __restrict__ q, const float* __restrict__ kT, const float* __restrict__ v,
    const float* __restrict__ qpg, const float* __restrict__ kpgT, const float* __restrict__ vpg,
    float* __restrict__ pb_attn, const float* __restrict__ pv,
    const float* __restrict__ R, const float* __restrict__ t,
    const float* __restrict__ point_weights, const float* __restrict__ mask,
    float* __restrict__ su_pre) {
  int i = blockIdx.x, tid = threadIdx.x;
  int h = tid >> 5, jl = tid & 31;

  __shared__ float sml[8*776];          // attn rows, stride 776 (=8*97, odd/32)
  __shared__ float sm_q[256];
  __shared__ float sm_qp[96];
  __shared__ float sm_mask[768];
  __shared__ float sm_ptg[192];
  __shared__ float sm_ptl[192];
  __shared__ float Rl[9], tl[3];

  sm_q[tid] = q[i*256 + tid];
  if (tid < 96) sm_qp[tid] = qpg[i*96 + tid];
  if (tid >= 96 && tid < 105) Rl[tid-96] = R[i*9 + (tid-96)];
  if (tid >= 112 && tid < 115) tl[tid-112] = t[i*3 + (tid-112)];
  #pragma unroll
  for (int rr=0; rr<3; rr++) sm_mask[rr*256 + tid] = mask[rr*256 + tid];
  __syncthreads();

  float pw = log1pf(__expf(point_weights[h]));
  float mi = mask[i];
  float qreg[32];
  #pragma unroll
  for (int c=0;c<32;c++) qreg[c] = sm_q[h*32+c];
  float qp_reg[12];
  #pragma unroll
  for (int pc=0;pc<12;pc++) qp_reg[pc] = sm_qp[h*12+pc];

  const float* kTb  = kT  + (size_t)(h*32)*L + jl;
  const float* kpTb = kpgT + (size_t)(h*12)*L + jl;
  const float* pbb  = pb_attn + (size_t)h*LL + (size_t)i*L + jl;

  // ---- phase 1: logits (24 j's per thread, fully coalesced loads) ----
  float lg[24];
  for (int jt=0; jt<24; jt++){
    int joff = jt*32;
    float dot = 0.f;
    #pragma unroll
    for (int c=0;c<32;c++) dot = fmaf(qreg[c], kTb[(size_t)c*L + joff], dot);
    float sq = 0.f;
    #pragma unroll
    for (int pc=0;pc<12;pc++){ float d = qp_reg[pc] - kpTb[(size_t)pc*L + joff]; sq = fmaf(d,d,sq); }
    float lgv = dot*0.17677669529663687f + pbb[joff] - 0.5f*pw*sq;
    if (mi*sm_mask[joff+jl] == 0.f) lgv = -1e9f;
    lg[jt] = lgv;
  }

  // ---- softmax across the 32-lane head group ----
  float m = -1e30f;
  #pragma unroll
  for (int jt=0; jt<24; jt++) m = fmaxf(m, lg[jt]);
  #pragma unroll
  for (int d=1; d<32; d<<=1) m = fmaxf(m, __shfl_xor(m, d));
  float ssum = 0.f;
  #pragma unroll
  for (int jt=0; jt<24; jt++){ float e = __expf(lg[jt]-m); lg[jt]=e; ssum+=e; }
  #pragma unroll
  for (int d=1; d<32; d<<=1) ssum += __shfl_xor(ssum, d);
  float inv = 1.0f/ssum;
  float* pbw = pb_attn + (size_t)h*LL + (size_t)i*L + jl;
  #pragma unroll
  for (int jt=0; jt<24; jt++){
    float a = lg[jt]*inv;
    sml[h*776 + jt*32 + jl] = a;
    pbw[jt*32] = a;                       // attn output (overwrites pair_bias slot)
  }
  __syncthreads();

  // ---- phase 2: weighted sums, one output per thread ----
  // tid 0..255: scalar_out o=tid (h=tid>>5)
  // tid 0..191: point global o=tid (h2=tid/24)
  // tid 192..223: pair o=tid-192 (h3=(tid-192)>>2)
  int h2 = (tid < 192) ? (tid/24) : ((tid < 224) ? ((tid-192)>>2) : 0);
  const float* src2; int stride2;
  if (tid < 192)      { src2 = vpg + tid;                                stride2 = 192; }
  else if (tid < 224) { src2 = pv + (size_t)i*L*32 + (tid-192);          stride2 = 32;  }
  else                { src2 = vpg + 0;                                  stride2 = 0;   }
  const float* vb = v + tid;
  const float* smlA = sml + h*776;
  const float* smlB = sml + h2*776;
  float acc_s = 0.f, acc2 = 0.f;
  #pragma unroll 4
  for (int j=0; j<768; j++){
    float a  = smlA[j];
    acc_s = fmaf(a, vb[(size_t)j*256], acc_s);
    float a2 = smlB[j];
    acc2 = fmaf(a2, src2[(size_t)j*stride2], acc2);
  }
  su_pre[i*544 + tid] = acc_s;
  if (tid < 192) sm_ptg[tid] = acc2;
  else if (tid < 224) su_pre[i*544 + 512 + (tid-192)] = acc2;
  __syncthreads();

  if (tid < 192){
    int hh = tid/24, rem = tid%24, p = rem/3, y = rem%3;
    float lv = 0.f;
    #pragma unroll
    for (int x=0;x<3;x++) lv = fmaf(Rl[x*3+y], sm_ptg[hh*24+p*3+x]-tl[x], lv);
    sm_ptl[tid] = lv;
    su_pre[i*544 + 256 + tid] = lv;
  }
  __syncthreads();
  if (tid < 64){
    float a0=sm_ptl[tid*3], a1=sm_ptl[tid*3+1], a2=sm_ptl[tid*3+2];
    su_pre[i*544 + 448 + tid] = sqrtf(a0*a0+a1*a1+a2*a2 + 1e-8f);
  }
}

// ---------------- K5: output projection ----------------
__global__ void k_out(const float* __restrict__ su_pre, const float* __restrict__ W_out,
                      const float* __restrict__ b_out, const float* __restrict__ mask,
                      float* __restrict__ out) {
  int i = blockIdx.x, tid = threadIdx.x;
  __shared__ float srow[544];
  for (int idx=tid; idx<544; idx+=256) srow[idx] = su_pre[i*544+idx];
  __syncthreads();
  float acc = b_out[tid];
  #pragma unroll 4
  for (int c=0;c<544;c++) acc = fmaf(srow[c], W_out[c*256+tid], acc);
  out[i*256+tid] = acc * mask[i];
}

extern "C" void kernel_launch(void* const* d_in, const int* in_sizes, int n_in,
                              void* d_out, int out_size, void* d_ws, size_t ws_size,
                              hipStream_t stream) {
  const float* s    = (const float*)d_in[0];
  const float* z    = (const float*)d_in[1];
  const float* R    = (const float*)d_in[2];
  const float* t    = (const float*)d_in[3];
  const float* mask = (const float*)d_in[4];
  const float* lsw  = (const float*)d_in[5];
  const float* lsb  = (const float*)d_in[6];
  const float* lzw  = (const float*)d_in[7];
  const float* lzb  = (const float*)d_in[8];
  const float* Wq   = (const float*)d_in[9];
  const float* Wk   = (const float*)d_in[10];
  const float* Wv   = (const float*)d_in[11];
  const float* Wpb  = (const float*)d_in[12];
  const float* Wqp  = (const float*)d_in[13];
  const float* Wkp  = (const float*)d_in[14];
  const float* Wvp  = (const float*)d_in[15];
  const float* pwts = (const float*)d_in[16];
  const float* Wpo  = (const float*)d_in[17];
  const float* Wout = (const float*)d_in[18];
  const float* bout = (const float*)d_in[19];

  float* out0 = (float*)d_out;
  float* attn = out0 + (size_t)L*CS;

  float* ws   = (float*)d_ws;
  float* s_n  = ws;                        size_t off = (size_t)L*CS;
  float* q    = ws + off;                  off += (size_t)L*CS;
  float* kT   = ws + off;                  off += (size_t)L*CS;
  float* v    = ws + off;                  off += (size_t)L*CS;
  float* qpg  = ws + off;                  off += (size_t)L*96;
  float* kpgT = ws + off;                  off += (size_t)L*96;
  float* vpg  = ws + off;                  off += (size_t)L*192;
  float* pv   = ws + off;                  off += (size_t)LL*32;
  float* su   = ws + off;                  off += (size_t)L*544;

  k_ln_s<<<L, 256, 0, stream>>>(s, lsw, lsb, s_n);
  k_proj<<<L, 256, 0, stream>>>(s_n, Wq, Wk, Wv, Wqp, Wkp, Wvp, R, t,
                                q, kT, v, qpg, kpgT, vpg);
  k_zfuse<<<dim3(L, L/64), 256, 0, stream>>>(z, lzw, lzb, Wpb, Wpo, attn, pv);
  k_attn_fused<<<L, 256, 0, stream>>>(q, kT, v, qpg, kpgT, vpg, attn, pv,
                                      R, t, pwts, mask, su);
  k_out<<<L, 256, 0, stream>>>(su, Wout, bout, mask, out0);
}

// Round 3
// 785.154 us; speedup vs baseline: 1.2974x; 1.1340x over previous
//
#include <hip/hip_runtime.h>
#include <math.h>

#define L 768
#define CS 256
#define CZ 128
#define H 8
#define LL (L*L)

typedef __attribute__((ext_vector_type(8))) short bf16x8;
typedef __attribute__((ext_vector_type(4))) float floatx4;

static __device__ __forceinline__ unsigned short f2bf(float f){
  unsigned int u = __float_as_uint(f);
  unsigned int r = (u + 0x7fffu + ((u >> 16) & 1u)) >> 16;
  return (unsigned short)r;
}

// ---------------- K1: LayerNorm over s rows ----------------
__global__ void k_ln_s(const float* __restrict__ s, const float* __restrict__ w,
                       const float* __restrict__ b, float* __restrict__ out) {
  int i = blockIdx.x, t = threadIdx.x;
  __shared__ float red[256];
  float x = s[i*CS + t];
  red[t] = x; __syncthreads();
  for (int s2=128; s2>0; s2>>=1){ if (t<s2) red[t]+=red[t+s2]; __syncthreads(); }
  float mean = red[0] * (1.0f/CS); __syncthreads();
  float d = x - mean;
  red[t] = d*d; __syncthreads();
  for (int s2=128; s2>0; s2>>=1){ if (t<s2) red[t]+=red[t+s2]; __syncthreads(); }
  float var = red[0] * (1.0f/CS);
  float rstd = rsqrtf(var + 1e-5f);
  out[i*CS+t] = d*rstd*w[t] + b[t];
}

// ---------------- K2: all projections of s + rigid transform ----------------
__global__ void k_proj(const float* __restrict__ s_n,
                       const float* __restrict__ Wq, const float* __restrict__ Wk, const float* __restrict__ Wv,
                       const float* __restrict__ Wqp, const float* __restrict__ Wkp, const float* __restrict__ Wvp,
                       const float* __restrict__ R, const float* __restrict__ t,
                       float* __restrict__ q, float* __restrict__ kT, float* __restrict__ v,
                       float* __restrict__ qpg, float* __restrict__ kpgT, float* __restrict__ vpg) {
  int i = blockIdx.x, tid = threadIdx.x;
  __shared__ float srow[256];
  __shared__ float qraw[96], kraw[96], vraw[192];
  __shared__ float Rl[9], tl[3];
  srow[tid] = s_n[i*CS + tid];
  if (tid < 9) Rl[tid] = R[i*9 + tid];
  if (tid >= 16 && tid < 19) tl[tid-16] = t[i*3 + (tid-16)];
  __syncthreads();
  float aq=0.f, ak=0.f, av=0.f;
  #pragma unroll 4
  for (int c=0;c<256;c++){ float sv=srow[c];
    aq = fmaf(sv, Wq[c*256+tid], aq);
    ak = fmaf(sv, Wk[c*256+tid], ak);
    av = fmaf(sv, Wv[c*256+tid], av); }
  q[i*256+tid]=aq; kT[(size_t)tid*L + i]=ak; v[i*256+tid]=av;
  if (tid < 96){
    float a1=0.f, a2=0.f;
    #pragma unroll 4
    for (int c=0;c<256;c++){ float sv=srow[c];
      a1 = fmaf(sv, Wqp[c*96+tid], a1);
      a2 = fmaf(sv, Wkp[c*96+tid], a2); }
    qraw[tid]=a1; kraw[tid]=a2;
  }
  if (tid < 192){
    float a3=0.f;
    #pragma unroll 4
    for (int c=0;c<256;c++) a3 = fmaf(srow[c], Wvp[c*192+tid], a3);
    vraw[tid]=a3;
  }
  __syncthreads();
  if (tid < 32){
    int b0 = tid*3;
    float px=qraw[b0], py=qraw[b0+1], pz=qraw[b0+2];
    #pragma unroll
    for (int x=0;x<3;x++)
      qpg[i*96 + b0 + x] = Rl[x*3]*px + Rl[x*3+1]*py + Rl[x*3+2]*pz + tl[x];
  } else if (tid < 64){
    int b0 = (tid-32)*3;
    float px=kraw[b0], py=kraw[b0+1], pz=kraw[b0+2];
    #pragma unroll
    for (int x=0;x<3;x++)
      kpgT[(size_t)(b0+x)*L + i] = Rl[x*3]*px + Rl[x*3+1]*py + Rl[x*3+2]*pz + tl[x];
  } else if (tid < 128){
    int b0 = (tid-64)*3;
    float px=vraw[b0], py=vraw[b0+1], pz=vraw[b0+2];
    #pragma unroll
    for (int x=0;x<3;x++)
      vpg[i*192 + b0 + x] = Rl[x*3]*px + Rl[x*3+1]*py + Rl[x*3+2]*pz + tl[x];
  }
}

// ---------------- K_prep: fold LN gain into W, pack B-fragments, compute u/v ----------------
// W_full(c,o) = o<8 ? Wpb[c*8+o] : (o<40 ? Wpo[c*32+o-8] : 0)
// Bpack[((nt*4+kb)*64+lane)*8+jj] = bf16( lzw[c]*W_full(c,o) ), c=kb*32+(lane>>4)*8+jj, o=nt*16+(lane&15)
// uv[o] = sum_c lzw[c]*W_full(c,o); uv[48+o] = sum_c lzb[c]*W_full(c,o)
__global__ void k_prep(const float* __restrict__ lzw, const float* __restrict__ lzb,
                       const float* __restrict__ Wpb, const float* __restrict__ Wpo,
                       unsigned short* __restrict__ Bpack, float* __restrict__ uv) {
  int tid = threadIdx.x;
  if (tid < 48){
    int o = tid;
    float uo = 0.f, vo = 0.f;
    for (int c=0;c<128;c++){
      float W = (o<8) ? Wpb[c*8+o] : ((o<40) ? Wpo[c*32+o-8] : 0.f);
      uo = fmaf(lzw[c], W, uo);
      vo = fmaf(lzb[c], W, vo);
    }
    uv[o] = uo; uv[48+o] = vo;
  }
  for (int idx=tid; idx<6144; idx+=256){
    int jj = idx & 7, lane = (idx>>3)&63, kb = (idx>>9)&3, nt = idx>>11;
    int c = kb*32 + (lane>>4)*8 + jj;
    int o = nt*16 + (lane&15);
    float W = (o<8) ? Wpb[c*8+o] : ((o<40) ? Wpo[c*32+o-8] : 0.f);
    Bpack[idx] = f2bf(lzw[c]*W);
  }
}

// ---------------- K3: z-pass with bf16 MFMA + folded LN ----------------
// Tile: one i, 64 consecutive j. 4 waves; wave w owns rows w*16..w*16+15 x all 48 outs.
__global__ __launch_bounds__(256) void k_zfuse(
    const float* __restrict__ z, const unsigned short* __restrict__ Bpack,
    const float* __restrict__ uv, float* __restrict__ pb, float* __restrict__ pv) {
  int i = blockIdx.x, jt = blockIdx.y, tid = threadIdx.x;
  int j0 = jt * 64;
  __shared__ unsigned short znb[64*136];   // bf16 z tile, row stride 136 (16B pad -> 2-way-free banks)
  __shared__ float smean[64], srstd[64];
  __shared__ float su[48], sv[48];

  if (tid < 48){ su[tid] = uv[tid]; sv[tid] = uv[48+tid]; }

  const float4* zb4 = (const float4*)(z + ((size_t)i*L + j0)*CZ);
  int lane31 = tid & 31;
  #pragma unroll
  for (int k=0;k<8;k++){
    int idx4 = k*256 + tid;          // float4 index; row = idx4>>5, col4 = idx4&31
    float4 v4 = zb4[idx4];
    int r = idx4 >> 5, c4 = idx4 & 31;
    float sm = v4.x+v4.y+v4.z+v4.w;
    float sq = v4.x*v4.x+v4.y*v4.y+v4.z*v4.z+v4.w*v4.w;
    #pragma unroll
    for (int d=1; d<32; d<<=1){ sm += __shfl_xor(sm,d); sq += __shfl_xor(sq,d); }
    if (lane31 == 0){
      float mean = sm*(1.f/128.f);
      float var  = sq*(1.f/128.f) - mean*mean;
      smean[r] = mean; srstd[r] = rsqrtf(var + 1e-5f);
    }
    ushort4 pk = make_ushort4(f2bf(v4.x), f2bf(v4.y), f2bf(v4.z), f2bf(v4.w));
    *(ushort4*)&znb[r*136 + c4*4] = pk;
  }
  __syncthreads();

  int w = tid >> 6;                   // wave id = m-tile
  int lane = tid & 63;
  int n16 = lane & 15, quad = lane >> 4;

  floatx4 acc0 = {0,0,0,0}, acc1 = {0,0,0,0}, acc2 = {0,0,0,0};
  const bf16x8* Bp = (const bf16x8*)Bpack;
  #pragma unroll
  for (int kb=0; kb<4; kb++){
    bf16x8 afrag = *(const bf16x8*)&znb[(w*16 + n16)*136 + kb*32 + quad*8];
    bf16x8 b0 = Bp[(0*4+kb)*64 + lane];
    bf16x8 b1 = Bp[(1*4+kb)*64 + lane];
    bf16x8 b2 = Bp[(2*4+kb)*64 + lane];
    acc0 = __builtin_amdgcn_mfma_f32_16x16x32_bf16(afrag, b0, acc0, 0,0,0);
    acc1 = __builtin_amdgcn_mfma_f32_16x16x32_bf16(afrag, b1, acc1, 0,0,0);
    acc2 = __builtin_amdgcn_mfma_f32_16x16x32_bf16(afrag, b2, acc2, 0,0,0);
  }

  // epilogue: out[j][o] = rstd_j*(acc - mean_j*u_o) + v_o
  #pragma unroll
  for (int nt=0; nt<3; nt++){
    int o = nt*16 + n16;
    if (o >= 40) continue;
    float uo = su[o], vo = sv[o];
    const floatx4 acc = (nt==0) ? acc0 : (nt==1) ? acc1 : acc2;
    #pragma unroll
    for (int reg=0; reg<4; reg++){
      int jl = w*16 + quad*4 + reg;
      int j = j0 + jl;
      float val = srstd[jl]*(acc[reg] - smean[jl]*uo) + vo;
      if (o < 8) pb[(size_t)o*LL + (size_t)i*L + j] = val;
      else       pv[((size_t)i*L + j)*32 + (o-8)] = val;
    }
  }
}

// ---------------- K4: fused attention, one block per i, all 8 heads ----------------
__global__ __launch_bounds__(256) void k_attn_fused(
    const float* __restrict__ q, const float* __restrict__ kT, const float* __restrict__ v,
    const float* __restrict__ qpg, const float* __restrict__ kpgT, const float* __restrict__ vpg,
    float* __restrict__ pb_attn, const float* __restrict__ pv,
    const float* __restrict__ R, const float* __restrict__ t,
    const float* __restrict__ point_weights, const float* __restrict__ mask,
    float* __restrict__ su_pre) {
  int i = blockIdx.x, tid = threadIdx.x;
  int h = tid >> 5, jl = tid & 31;

  __shared__ float sml[8*776];
  __shared__ float sm_q[256];
  __shared__ float sm_qp[96];
  __shared__ float sm_mask[768];
  __shared__ float sm_ptg[192];
  __shared__ float sm_ptl[192];
  __shared__ float Rl[9], tl[3];

  sm_q[tid] = q[i*256 + tid];
  if (tid < 96) sm_qp[tid] = qpg[i*96 + tid];
  if (tid >= 96 && tid < 105) Rl[tid-96] = R[i*9 + (tid-96)];
  if (tid >= 112 && tid < 115) tl[tid-112] = t[i*3 + (tid-112)];
  #pragma unroll
  for (int rr=0; rr<3; rr++) sm_mask[rr*256 + tid] = mask[rr*256 + tid];
  __syncthreads();

  float pw = log1pf(__expf(point_weights[h]));
  float mi = mask[i];
  float qreg[32];
  #pragma unroll
  for (int c=0;c<32;c++) qreg[c] = sm_q[h*32+c];
  float qp_reg[12];
  #pragma unroll
  for (int pc=0;pc<12;pc++) qp_reg[pc] = sm_qp[h*12+pc];

  const float* kTb  = kT  + (size_t)(h*32)*L + jl;
  const float* kpTb = kpgT + (size_t)(h*12)*L + jl;
  const float* pbb  = pb_attn + (size_t)h*LL + (size_t)i*L + jl;

  float lg[24];
  for (int jt=0; jt<24; jt++){
    int joff = jt*32;
    float dot = 0.f;
    #pragma unroll
    for (int c=0;c<32;c++) dot = fmaf(qreg[c], kTb[(size_t)c*L + joff], dot);
    float sq = 0.f;
    #pragma unroll
    for (int pc=0;pc<12;pc++){ float d = qp_reg[pc] - kpTb[(size_t)pc*L + joff]; sq = fmaf(d,d,sq); }
    float lgv = dot*0.17677669529663687f + pbb[joff] - 0.5f*pw*sq;
    if (mi*sm_mask[joff+jl] == 0.f) lgv = -1e9f;
    lg[jt] = lgv;
  }

  float m = -1e30f;
  #pragma unroll
  for (int jt=0; jt<24; jt++) m = fmaxf(m, lg[jt]);
  #pragma unroll
  for (int d=1; d<32; d<<=1) m = fmaxf(m, __shfl_xor(m, d));
  float ssum = 0.f;
  #pragma unroll
  for (int jt=0; jt<24; jt++){ float e = __expf(lg[jt]-m); lg[jt]=e; ssum+=e; }
  #pragma unroll
  for (int d=1; d<32; d<<=1) ssum += __shfl_xor(ssum, d);
  float inv = 1.0f/ssum;
  float* pbw = pb_attn + (size_t)h*LL + (size_t)i*L + jl;
  #pragma unroll
  for (int jt=0; jt<24; jt++){
    float a = lg[jt]*inv;
    sml[h*776 + jt*32 + jl] = a;
    pbw[jt*32] = a;
  }
  __syncthreads();

  int h2 = (tid < 192) ? (tid/24) : ((tid < 224) ? ((tid-192)>>2) : 0);
  const float* src2; int stride2;
  if (tid < 192)      { src2 = vpg + tid;                                stride2 = 192; }
  else if (tid < 224) { src2 = pv + (size_t)i*L*32 + (tid-192);          stride2 = 32;  }
  else                { src2 = vpg + 0;                                  stride2 = 0;   }
  const float* vb = v + tid;
  const float* smlA = sml + h*776;
  const float* smlB = sml + h2*776;
  float acc_s = 0.f, acc2 = 0.f;
  #pragma unroll 4
  for (int j=0; j<768; j++){
    float a  = smlA[j];
    acc_s = fmaf(a, vb[(size_t)j*256], acc_s);
    float a2 = smlB[j];
    acc2 = fmaf(a2, src2[(size_t)j*stride2], acc2);
  }
  su_pre[i*544 + tid] = acc_s;
  if (tid < 192) sm_ptg[tid] = acc2;
  else if (tid < 224) su_pre[i*544 + 512 + (tid-192)] = acc2;
  __syncthreads();

  if (tid < 192){
    int hh = tid/24, rem = tid%24, p = rem/3, y = rem%3;
    float lv = 0.f;
    #pragma unroll
    for (int x=0;x<3;x++) lv = fmaf(Rl[x*3+y], sm_ptg[hh*24+p*3+x]-tl[x], lv);
    sm_ptl[tid] = lv;
    su_pre[i*544 + 256 + tid] = lv;
  }
  __syncthreads();
  if (tid < 64){
    float a0=sm_ptl[tid*3], a1=sm_ptl[tid*3+1], a2=sm_ptl[tid*3+2];
    su_pre[i*544 + 448 + tid] = sqrtf(a0*a0+a1*a1+a2*a2 + 1e-8f);
  }
}

// ---------------- K5: output projection ----------------
__global__ void k_out(const float* __restrict__ su_pre, const float* __restrict__ W_out,
                      const float* __restrict__ b_out, const float* __restrict__ mask,
                      float* __restrict__ out) {
  int i = blockIdx.x, tid = threadIdx.x;
  __shared__ float srow[544];
  for (int idx=tid; idx<544; idx+=256) srow[idx] = su_pre[i*544+idx];
  __syncthreads();
  float acc = b_out[tid];
  #pragma unroll 4
  for (int c=0;c<544;c++) acc = fmaf(srow[c], W_out[c*256+tid], acc);
  out[i*256+tid] = acc * mask[i];
}

extern "C" void kernel_launch(void* const* d_in, const int* in_sizes, int n_in,
                              void* d_out, int out_size, void* d_ws, size_t ws_size,
                              hipStream_t stream) {
  const float* s    = (const float*)d_in[0];
  const float* z    = (const float*)d_in[1];
  const float* R    = (const float*)d_in[2];
  const float* t    = (const float*)d_in[3];
  const float* mask = (const float*)d_in[4];
  const float* lsw  = (const float*)d_in[5];
  const float* lsb  = (const float*)d_in[6];
  const float* lzw  = (const float*)d_in[7];
  const float* lzb  = (const float*)d_in[8];
  const float* Wq   = (const float*)d_in[9];
  const float* Wk   = (const float*)d_in[10];
  const float* Wv   = (const float*)d_in[11];
  const float* Wpb  = (const float*)d_in[12];
  const float* Wqp  = (const float*)d_in[13];
  const float* Wkp  = (const float*)d_in[14];
  const float* Wvp  = (const float*)d_in[15];
  const float* pwts = (const float*)d_in[16];
  const float* Wpo  = (const float*)d_in[17];
  const float* Wout = (const float*)d_in[18];
  const float* bout = (const float*)d_in[19];

  float* out0 = (float*)d_out;
  float* attn = out0 + (size_t)L*CS;

  float* ws   = (float*)d_ws;
  float* s_n  = ws;                        size_t off = (size_t)L*CS;
  float* q    = ws + off;                  off += (size_t)L*CS;
  float* kT   = ws + off;                  off += (size_t)L*CS;
  float* v    = ws + off;                  off += (size_t)L*CS;
  float* qpg  = ws + off;                  off += (size_t)L*96;
  float* kpgT = ws + off;                  off += (size_t)L*96;
  float* vpg  = ws + off;                  off += (size_t)L*192;
  float* pv   = ws + off;                  off += (size_t)LL*32;
  float* su   = ws + off;                  off += (size_t)L*544;
  unsigned short* Bpack = (unsigned short*)(ws + off); off += 3072;  // 6144 bf16
  float* uv   = ws + off;                  off += 96;

  k_prep<<<1, 256, 0, stream>>>(lzw, lzb, Wpb, Wpo, Bpack, uv);
  k_ln_s<<<L, 256, 0, stream>>>(s, lsw, lsb, s_n);
  k_proj<<<L, 256, 0, stream>>>(s_n, Wq, Wk, Wv, Wqp, Wkp, Wvp, R, t,
                                q, kT, v, qpg, kpgT, vpg);
  k_zfuse<<<dim3(L, L/64), 256, 0, stream>>>(z, Bpack, uv, attn, pv);
  k_attn_fused<<<L, 256, 0, stream>>>(q, kT, v, qpg, kpgT, vpg, attn, pv,
                                      R, t, pwts, mask, su);
  k_out<<<L, 256, 0, stream>>>(su, Wout, bout, mask, out0);
}

// Round 4
// 776.729 us; speedup vs baseline: 1.3115x; 1.0108x over previous
//
#include <hip/hip_runtime.h>
#include <math.h>

#define L 768
#define CS 256
#define CZ 128
#define H 8
#define LL (L*L)

typedef __attribute__((ext_vector_type(8))) short bf16x8;
typedef __attribute__((ext_vector_type(4))) float floatx4;

static __device__ __forceinline__ unsigned short f2bf(float f){
  unsigned int u = __float_as_uint(f);
  unsigned int r = (u + 0x7fffu + ((u >> 16) & 1u)) >> 16;
  return (unsigned short)r;
}

// ---------------- K1: LayerNorm over s rows ----------------
__global__ void k_ln_s(const float* __restrict__ s, const float* __restrict__ w,
                       const float* __restrict__ b, float* __restrict__ out) {
  int i = blockIdx.x, t = threadIdx.x;
  __shared__ float red[256];
  float x = s[i*CS + t];
  red[t] = x; __syncthreads();
  for (int s2=128; s2>0; s2>>=1){ if (t<s2) red[t]+=red[t+s2]; __syncthreads(); }
  float mean = red[0] * (1.0f/CS); __syncthreads();
  float d = x - mean;
  red[t] = d*d; __syncthreads();
  for (int s2=128; s2>0; s2>>=1){ if (t<s2) red[t]+=red[t+s2]; __syncthreads(); }
  float var = red[0] * (1.0f/CS);
  float rstd = rsqrtf(var + 1e-5f);
  out[i*CS+t] = d*rstd*w[t] + b[t];
}

// ---------------- K2: projections of s + rigid transform, 2 rows/block ----------------
__global__ void k_proj(const float* __restrict__ s_n,
                       const float* __restrict__ Wq, const float* __restrict__ Wk, const float* __restrict__ Wv,
                       const float* __restrict__ Wqp, const float* __restrict__ Wkp, const float* __restrict__ Wvp,
                       const float* __restrict__ R, const float* __restrict__ t,
                       float* __restrict__ q, float* __restrict__ kT, float* __restrict__ v,
                       float* __restrict__ qpg, float* __restrict__ kpgT, float* __restrict__ vpg) {
  int i0 = blockIdx.x*2, tid = threadIdx.x;
  __shared__ float srow[2][256];
  __shared__ float qraw[2][96], kraw[2][96], vraw[2][192];
  __shared__ float Rl[2][9], tl[2][3];
  srow[0][tid] = s_n[i0*CS + tid];
  srow[1][tid] = s_n[(i0+1)*CS + tid];
  if (tid < 18) Rl[tid/9][tid%9] = R[i0*9 + tid];
  if (tid >= 24 && tid < 30) tl[(tid-24)/3][(tid-24)%3] = t[i0*3 + (tid-24)];
  __syncthreads();
  float aq0=0.f, ak0=0.f, av0=0.f, aq1=0.f, ak1=0.f, av1=0.f;
  #pragma unroll 4
  for (int c=0;c<256;c++){
    float s0=srow[0][c], s1=srow[1][c];
    float wq=Wq[c*256+tid], wk=Wk[c*256+tid], wv=Wv[c*256+tid];
    aq0=fmaf(s0,wq,aq0); aq1=fmaf(s1,wq,aq1);
    ak0=fmaf(s0,wk,ak0); ak1=fmaf(s1,wk,ak1);
    av0=fmaf(s0,wv,av0); av1=fmaf(s1,wv,av1);
  }
  q[i0*256+tid]=aq0; q[(i0+1)*256+tid]=aq1;
  kT[(size_t)tid*L + i0]=ak0; kT[(size_t)tid*L + i0+1]=ak1;
  v[i0*256+tid]=av0; v[(i0+1)*256+tid]=av1;
  if (tid < 96){
    float a10=0.f,a20=0.f,a11=0.f,a21=0.f;
    #pragma unroll 4
    for (int c=0;c<256;c++){
      float s0=srow[0][c], s1=srow[1][c];
      float w1=Wqp[c*96+tid], w2=Wkp[c*96+tid];
      a10=fmaf(s0,w1,a10); a11=fmaf(s1,w1,a11);
      a20=fmaf(s0,w2,a20); a21=fmaf(s1,w2,a21);
    }
    qraw[0][tid]=a10; qraw[1][tid]=a11; kraw[0][tid]=a20; kraw[1][tid]=a21;
  }
  if (tid < 192){
    float a30=0.f,a31=0.f;
    #pragma unroll 4
    for (int c=0;c<256;c++){
      float w3=Wvp[c*192+tid];
      a30=fmaf(srow[0][c],w3,a30); a31=fmaf(srow[1][c],w3,a31);
    }
    vraw[0][tid]=a30; vraw[1][tid]=a31;
  }
  __syncthreads();
  #pragma unroll
  for (int rr=0; rr<2; rr++){
    int i = i0 + rr;
    if (tid < 32){
      int b0 = tid*3;
      float px=qraw[rr][b0], py=qraw[rr][b0+1], pz=qraw[rr][b0+2];
      #pragma unroll
      for (int x=0;x<3;x++)
        qpg[i*96 + b0 + x] = Rl[rr][x*3]*px + Rl[rr][x*3+1]*py + Rl[rr][x*3+2]*pz + tl[rr][x];
    } else if (tid < 64){
      int b0 = (tid-32)*3;
      float px=kraw[rr][b0], py=kraw[rr][b0+1], pz=kraw[rr][b0+2];
      #pragma unroll
      for (int x=0;x<3;x++)
        kpgT[(size_t)(b0+x)*L + i] = Rl[rr][x*3]*px + Rl[rr][x*3+1]*py + Rl[rr][x*3+2]*pz + tl[rr][x];
    } else if (tid < 128){
      int b0 = (tid-64)*3;
      float px=vraw[rr][b0], py=vraw[rr][b0+1], pz=vraw[rr][b0+2];
      #pragma unroll
      for (int x=0;x<3;x++)
        vpg[i*192 + b0 + x] = Rl[rr][x*3]*px + Rl[rr][x*3+1]*py + Rl[rr][x*3+2]*pz + tl[rr][x];
    }
  }
}

// ---------------- K_prep: fold LN gain into W, pack B-fragments, compute u/v ----------------
__global__ void k_prep(const float* __restrict__ lzw, const float* __restrict__ lzb,
                       const float* __restrict__ Wpb, const float* __restrict__ Wpo,
                       unsigned short* __restrict__ Bpack, float* __restrict__ uv) {
  int tid = threadIdx.x;
  if (tid < 48){
    int o = tid;
    float uo = 0.f, vo = 0.f;
    for (int c=0;c<128;c++){
      float W = (o<8) ? Wpb[c*8+o] : ((o<40) ? Wpo[c*32+o-8] : 0.f);
      uo = fmaf(lzw[c], W, uo);
      vo = fmaf(lzb[c], W, vo);
    }
    uv[o] = uo; uv[48+o] = vo;
  }
  for (int idx=tid; idx<6144; idx+=256){
    int jj = idx & 7, lane = (idx>>3)&63, kb = (idx>>9)&3, nt = idx>>11;
    int c = kb*32 + (lane>>4)*8 + jj;
    int o = nt*16 + (lane&15);
    float W = (o<8) ? Wpb[c*8+o] : ((o<40) ? Wpo[c*32+o-8] : 0.f);
    Bpack[idx] = f2bf(lzw[c]*W);
  }
}

// ---------------- K3: z-pass, bf16 MFMA + folded LN, 128-j tile, barrier-free ----------------
__global__ __launch_bounds__(256) void k_zfuse(
    const float* __restrict__ z, const unsigned short* __restrict__ Bpack,
    const float* __restrict__ uv, float* __restrict__ pb, float* __restrict__ pv) {
  int i = blockIdx.x, jt = blockIdx.y, tid = threadIdx.x;
  int j0 = jt * 128;
  __shared__ unsigned short znb[128*136];   // bf16 z tile, stride 136
  __shared__ float smean[128], srstd[128];

  int lane = tid & 63;
  // hoist B fragments (whole Bpack, reused across both m-tiles)
  const bf16x8* Bp = (const bf16x8*)Bpack;
  bf16x8 bfr[3][4];
  #pragma unroll
  for (int nt=0; nt<3; nt++)
    #pragma unroll
    for (int kb=0; kb<4; kb++)
      bfr[nt][kb] = Bp[(nt*4+kb)*64 + lane];

  // staging: 2 threads per row -> register stats, single shuffle round
  int row = tid >> 1, sub = tid & 1;
  const float4* zrow = (const float4*)(z + ((size_t)i*L + j0 + row)*CZ);
  float sm = 0.f, sq = 0.f;
  #pragma unroll 8
  for (int kk=0; kk<16; kk++){
    float4 v4 = zrow[sub + 2*kk];
    sm += (v4.x+v4.y)+(v4.z+v4.w);
    sq = fmaf(v4.x,v4.x, fmaf(v4.y,v4.y, fmaf(v4.z,v4.z, fmaf(v4.w,v4.w, sq))));
    ushort4 pk = make_ushort4(f2bf(v4.x), f2bf(v4.y), f2bf(v4.z), f2bf(v4.w));
    *(ushort4*)&znb[row*136 + (sub+2*kk)*4] = pk;
  }
  sm += __shfl_xor(sm,1); sq += __shfl_xor(sq,1);
  if (sub == 0){
    float mean = sm*(1.f/128.f);
    float var  = sq*(1.f/128.f) - mean*mean;
    smean[row] = mean; srstd[row] = rsqrtf(var + 1e-5f);
  }
  // NO __syncthreads: each wave's MFMA rows == the rows it staged (same-wave LDS RAW)

  int w = tid >> 6;
  int n16 = lane & 15, quad = lane >> 4;
  #pragma unroll
  for (int mt2=0; mt2<2; mt2++){
    int mt = w*2 + mt2;                      // rows mt*16 .. mt*16+15  (within wave's 32 rows)
    floatx4 acc0 = {0,0,0,0}, acc1 = {0,0,0,0}, acc2 = {0,0,0,0};
    #pragma unroll
    for (int kb=0; kb<4; kb++){
      bf16x8 afrag = *(const bf16x8*)&znb[(mt*16 + n16)*136 + kb*32 + quad*8];
      acc0 = __builtin_amdgcn_mfma_f32_16x16x32_bf16(afrag, bfr[0][kb], acc0, 0,0,0);
      acc1 = __builtin_amdgcn_mfma_f32_16x16x32_bf16(afrag, bfr[1][kb], acc1, 0,0,0);
      acc2 = __builtin_amdgcn_mfma_f32_16x16x32_bf16(afrag, bfr[2][kb], acc2, 0,0,0);
    }
    #pragma unroll
    for (int nt=0; nt<3; nt++){
      int o = nt*16 + n16;
      if (o >= 40) continue;
      float uo = uv[o], vo = uv[48+o];
      const floatx4 acc = (nt==0) ? acc0 : (nt==1) ? acc1 : acc2;
      #pragma unroll
      for (int reg=0; reg<4; reg++){
        int jl = mt*16 + quad*4 + reg;
        int j = j0 + jl;
        float val = srstd[jl]*(acc[reg] - smean[jl]*uo) + vo;
        if (o < 8) pb[(size_t)o*LL + (size_t)i*L + j] = val;
        else       pv[((size_t)i*L + j)*32 + (o-8)] = val;
      }
    }
  }
}

// ---------------- K4: fused attention, one block per i, all 8 heads ----------------
__global__ __launch_bounds__(256) void k_attn_fused(
    const float* __restrict__ q, const float* __restrict__ kT, const float* __restrict__ v,
    const float* __restrict__ qpg, const float* __restrict__ kpgT, const float* __restrict__ vpg,
    float* __restrict__ pb_attn, const float* __restrict__ pv,
    const float* __restrict__ R, const float* __restrict__ t,
    const float* __restrict__ point_weights, const float* __restrict__ mask,
    float* __restrict__ su_pre) {
  int i = blockIdx.x, tid = threadIdx.x;
  int h = tid >> 5, jl = tid & 31;

  __shared__ float sml[8*776];
  __shared__ float sm_q[256];
  __shared__ float sm_qp[96];
  __shared__ float sm_mask[768];
  __shared__ float sm_ptg[192];
  __shared__ float sm_ptl[192];
  __shared__ float Rl[9], tl[3];

  sm_q[tid] = q[i*256 + tid];
  if (tid < 96) sm_qp[tid] = qpg[i*96 + tid];
  if (tid >= 96 && tid < 105) Rl[tid-96] = R[i*9 + (tid-96)];
  if (tid >= 112 && tid < 115) tl[tid-112] = t[i*3 + (tid-112)];
  #pragma unroll
  for (int rr=0; rr<3; rr++) sm_mask[rr*256 + tid] = mask[rr*256 + tid];
  __syncthreads();

  float pw = log1pf(__expf(point_weights[h]));
  float mi = mask[i];
  float qreg[32];
  #pragma unroll
  for (int c=0;c<32;c++) qreg[c] = sm_q[h*32+c];
  float qp_reg[12];
  #pragma unroll
  for (int pc=0;pc<12;pc++) qp_reg[pc] = sm_qp[h*12+pc];

  const float* kTb  = kT  + (size_t)(h*32)*L + jl;
  const float* kpTb = kpgT + (size_t)(h*12)*L + jl;
  const float* pbb  = pb_attn + (size_t)h*LL + (size_t)i*L + jl;

  float lg[24];
  for (int jt=0; jt<24; jt++){
    int joff = jt*32;
    float dot = 0.f;
    #pragma unroll
    for (int c=0;c<32;c++) dot = fmaf(qreg[c], kTb[(size_t)c*L + joff], dot);
    float sq = 0.f;
    #pragma unroll
    for (int pc=0;pc<12;pc++){ float d = qp_reg[pc] - kpTb[(size_t)pc*L + joff]; sq = fmaf(d,d,sq); }
    float lgv = dot*0.17677669529663687f + pbb[joff] - 0.5f*pw*sq;
    if (mi*sm_mask[joff+jl] == 0.f) lgv = -1e9f;
    lg[jt] = lgv;
  }

  float m = -1e30f;
  #pragma unroll
  for (int jt=0; jt<24; jt++) m = fmaxf(m, lg[jt]);
  #pragma unroll
  for (int d=1; d<32; d<<=1) m = fmaxf(m, __shfl_xor(m, d));
  float ssum = 0.f;
  #pragma unroll
  for (int jt=0; jt<24; jt++){ float e = __expf(lg[jt]-m); lg[jt]=e; ssum+=e; }
  #pragma unroll
  for (int d=1; d<32; d<<=1) ssum += __shfl_xor(ssum, d);
  float inv = 1.0f/ssum;
  float* pbw = pb_attn + (size_t)h*LL + (size_t)i*L + jl;
  #pragma unroll
  for (int jt=0; jt<24; jt++){
    float a = lg[jt]*inv;
    sml[h*776 + jt*32 + jl] = a;
    pbw[jt*32] = a;
  }
  __syncthreads();

  // ---- phase 2: 240 uniform float2 jobs ----
  // job<128: scalar pair (h=job>>4, outs job*2,job*2+1)
  // 128..223: ptg element pair e2=(job-128)*2, h=e2/24
  // 224..239: pair-out pair e2=(job-224)*2, h=e2>>2
  const float2* src; int str; const float* smlB;
  if (tid < 128)      { src = (const float2*)v + tid;                         str = 128; smlB = sml + (tid>>4)*776; }
  else if (tid < 224) { int e2=(tid-128)*2; src = (const float2*)vpg + (tid-128); str = 96; smlB = sml + (e2/24)*776; }
  else if (tid < 240) { int e2=(tid-224)*2; src = (const float2*)(pv + (size_t)i*L*32) + (tid-224); str = 16; smlB = sml + (e2>>2)*776; }
  else                { src = (const float2*)v; str = 0; smlB = sml; }
  float2 acc = {0.f, 0.f};
  #pragma unroll 8
  for (int j=0; j<768; j++){
    float a = smlB[j];
    float2 vv = src[(size_t)j*str];
    acc.x = fmaf(a, vv.x, acc.x);
    acc.y = fmaf(a, vv.y, acc.y);
  }
  if (tid < 128)      *(float2*)&su_pre[i*544 + tid*2] = acc;
  else if (tid < 224) { int e2=(tid-128)*2; sm_ptg[e2] = acc.x; sm_ptg[e2+1] = acc.y; }
  else if (tid < 240) *(float2*)&su_pre[i*544 + 512 + (tid-224)*2] = acc;
  __syncthreads();

  if (tid < 192){
    int hh = tid/24, rem = tid%24, p = rem/3, y = rem%3;
    float lv = 0.f;
    #pragma unroll
    for (int x=0;x<3;x++) lv = fmaf(Rl[x*3+y], sm_ptg[hh*24+p*3+x]-tl[x], lv);
    sm_ptl[tid] = lv;
    su_pre[i*544 + 256 + tid] = lv;
  }
  __syncthreads();
  if (tid < 64){
    float a0=sm_ptl[tid*3], a1=sm_ptl[tid*3+1], a2=sm_ptl[tid*3+2];
    su_pre[i*544 + 448 + tid] = sqrtf(a0*a0+a1*a1+a2*a2 + 1e-8f);
  }
}

// ---------------- K5: output projection ----------------
__global__ void k_out(const float* __restrict__ su_pre, const float* __restrict__ W_out,
                      const float* __restrict__ b_out, const float* __restrict__ mask,
                      float* __restrict__ out) {
  int i = blockIdx.x, tid = threadIdx.x;
  __shared__ float srow[544];
  for (int idx=tid; idx<544; idx+=256) srow[idx] = su_pre[i*544+idx];
  __syncthreads();
  float acc = b_out[tid];
  #pragma unroll 4
  for (int c=0;c<544;c++) acc = fmaf(srow[c], W_out[c*256+tid], acc);
  out[i*256+tid] = acc * mask[i];
}

extern "C" void kernel_launch(void* const* d_in, const int* in_sizes, int n_in,
                              void* d_out, int out_size, void* d_ws, size_t ws_size,
                              hipStream_t stream) {
  const float* s    = (const float*)d_in[0];
  const float* z    = (const float*)d_in[1];
  const float* R    = (const float*)d_in[2];
  const float* t    = (const float*)d_in[3];
  const float* mask = (const float*)d_in[4];
  const float* lsw  = (const float*)d_in[5];
  const float* lsb  = (const float*)d_in[6];
  const float* lzw  = (const float*)d_in[7];
  const float* lzb  = (const float*)d_in[8];
  const float* Wq   = (const float*)d_in[9];
  const float* Wk   = (const float*)d_in[10];
  const float* Wv   = (const float*)d_in[11];
  const float* Wpb  = (const float*)d_in[12];
  const float* Wqp  = (const float*)d_in[13];
  const float* Wkp  = (const float*)d_in[14];
  const float* Wvp  = (const float*)d_in[15];
  const float* pwts = (const float*)d_in[16];
  const float* Wpo  = (const float*)d_in[17];
  const float* Wout = (const float*)d_in[18];
  const float* bout = (const float*)d_in[19];

  float* out0 = (float*)d_out;
  float* attn = out0 + (size_t)L*CS;

  float* ws   = (float*)d_ws;
  float* s_n  = ws;                        size_t off = (size_t)L*CS;
  float* q    = ws + off;                  off += (size_t)L*CS;
  float* kT   = ws + off;                  off += (size_t)L*CS;
  float* v    = ws + off;                  off += (size_t)L*CS;
  float* qpg  = ws + off;                  off += (size_t)L*96;
  float* kpgT = ws + off;                  off += (size_t)L*96;
  float* vpg  = ws + off;                  off += (size_t)L*192;
  float* pv   = ws + off;                  off += (size_t)LL*32;
  float* su   = ws + off;                  off += (size_t)L*544;
  unsigned short* Bpack = (unsigned short*)(ws + off); off += 3072;  // 6144 bf16
  float* uv   = ws + off;                  off += 96;

  k_prep<<<1, 256, 0, stream>>>(lzw, lzb, Wpb, Wpo, Bpack, uv);
  k_ln_s<<<L, 256, 0, stream>>>(s, lsw, lsb, s_n);
  k_proj<<<L/2, 256, 0, stream>>>(s_n, Wq, Wk, Wv, Wqp, Wkp, Wvp, R, t,
                                  q, kT, v, qpg, kpgT, vpg);
  k_zfuse<<<dim3(L, L/128), 256, 0, stream>>>(z, Bpack, uv, attn, pv);
  k_attn_fused<<<L, 256, 0, stream>>>(q, kT, v, qpg, kpgT, vpg, attn, pv,
                                      R, t, pwts, mask, su);
  k_out<<<L, 256, 0, stream>>>(su, Wout, bout, mask, out0);
}